// Round 1
// baseline (259.953 us; speedup 1.0000x reference)
//
#include <hip/hip_runtime.h>
#include <cstdint>
#include <cstddef>

// Problem constants (from reference: B=2, P=8192, K=20)
#define PBUF 8192
#define NZB 256            // z bins
#define NYB 32             // y bins within each z bin (lexicographic sort key)
#define NBINS (NZB * NYB)  // 8192 flat bins per combo
#define NCOMBO 4           // (side, batch) combos: c = side*2 + b
#define KNN 20
#define CAP 256            // survivor cap per query (expected <=130)

// binning: transformed coords bounded by ~|v|<=64; [-72,72] covers all
#define ZMIN_F (-72.0f)
#define INV_BINW (256.0f / 144.0f)
#define INV_YBINW (32.0f / 144.0f)

#define IDX_MASK 0x1FFFu
#define D2_MASK 0xFFFFE000u
#define KEY_INF 0xFFFFFFFFu

// eps-filter: terms with d2 > 21*ls contribute < 2exp(-21) each; worst-case induced
// output error <= ~1e-9 << 1.69e-8 abs threshold (ref value ~8.5e-7).
#define THR_MULT 21.0f

// workspace layout (bytes)
#define OFF_ACCUM   0                                       // 512 floats: [side][256 cells]
#define OFF_DONE    2048                                    // done-counter (fused final)
#define OFF_DBSTART 2064                                    // 4 * 8193 ints (flat (z,y) prefix)
#define OFF_DBCUR   (OFF_DBSTART + NCOMBO * (NBINS + 1) * 4)   // 4 * 8192 ints (cursors)
#define OFF_DBPOS   (OFF_DBCUR + NCOMBO * NBINS * 4)        // 264224, 16-aligned
#define ARR_BYTES   (NCOMBO * PBUF * 16)                    // 524288 per float4 array
#define OFF_DBF1    (OFF_DBPOS + ARR_BYTES)
#define OFF_DBF2    (OFF_DBF1 + ARR_BYTES)
// total ws use ~1.84 MB

__device__ __forceinline__ int binOfZ(float z) {
  int b = (int)floorf((z - ZMIN_F) * INV_BINW);
  return min(max(b, 0), NZB - 1);
}
__device__ __forceinline__ int binOfY(float y) {
  int b = (int)floorf((y - ZMIN_F) * INV_YBINW);
  return min(max(b, 0), NYB - 1);
}

// Pinned fma order so count-kernel and scatter-kernel binning agree bit-exactly.
__device__ __forceinline__ float xformRow(const float* R, float tr, float x0, float x1, float x2) {
  return __fmaf_rn(R[2], x2, __fmaf_rn(R[1], x1, __fmaf_rn(R[0], x0, tr)));
}

// ---------------- K1: fused zero + count + prefix. One block per combo, LDS histogram.
// Replaces {memset, k_count, k_prefix} = 3 dispatches with 1, and skips global count atomics.
__global__ __launch_bounds__(256) void k_cp(
    const float* xyz1, const float* xyz2,
    const float* R12, const float* t12,
    const float* R21, const float* t21,
    const int* npts1, const int* npts2, char* ws) {
  __shared__ int hist[NBINS];   // 32 KB
  __shared__ int sTot[256];
  const int c = blockIdx.x, t = threadIdx.x;
  const int s = c >> 1, b = c & 1;

  #pragma unroll
  for (int k = 0; k < 32; ++k) hist[t + 256 * k] = 0;
  if (c == 0) {                 // zero accum cells + done counter (words [0,516))
    int* z = (int*)ws;
    for (int i = t; i < 516; i += 256) z[i] = 0;
  }
  __syncthreads();

  const float* dsrc = s == 0 ? xyz2 : xyz1;
  const float* R  = (s == 0 ? R12 : R21) + b * 9;
  const float* tt = (s == 0 ? t12 : t21) + b * 3;
  const int ldb = (s == 0 ? npts2 : npts1)[b];

  for (int j = t; j < PBUF; j += 256) {
    if (j < ldb) {
      const float* x = dsrc + (size_t)(b * PBUF + j) * 3;
      float x0 = x[0], x1 = x[1], x2 = x[2];
      float y1 = xformRow(R + 3, tt[1], x0, x1, x2);
      float y2 = xformRow(R + 6, tt[2], x0, x1, x2);
      int bin = binOfZ(y2) * NYB + binOfY(y1);
      atomicAdd(&hist[bin], 1);
    }
  }
  __syncthreads();

  // exclusive prefix over 8192 bins: 32 per thread + 256-wide shared scan
  int vals[32];
  int base = t * 32;
  int sum = 0;
  #pragma unroll
  for (int k = 0; k < 32; ++k) { vals[k] = hist[base + k]; sum += vals[k]; }
  sTot[t] = sum;
  __syncthreads();
  for (int o = 1; o < 256; o <<= 1) {
    int v = (t >= o) ? sTot[t - o] : 0;
    __syncthreads();
    sTot[t] += v;
    __syncthreads();
  }
  int run = sTot[t] - sum;
  int* st  = (int*)(ws + OFF_DBSTART) + c * (NBINS + 1);
  int* cnt = (int*)(ws + OFF_DBCUR) + c * NBINS;
  #pragma unroll
  for (int k = 0; k < 32; ++k) {
    st[base + k] = run;
    cnt[base + k] = run;     // cursor init
    run += vals[k];
  }
  if (t == 255) st[NBINS] = run;
}

// ---------------- K2: scatter transformed db points + features, (z,y)-lexicographic order ----------------
__global__ void k_scatter(const float* xyz1, const float* xyz2,
                          const float* hsv1, const float* hsv2,
                          const float* normal1, const float* normal2,
                          const float* nres1, const float* nres2,
                          const float* R12, const float* t12,
                          const float* R21, const float* t21,
                          const int* npts1, const int* npts2, char* ws) {
  int tid = blockIdx.x * 256 + threadIdx.x;
  int c = tid >> 13, j = tid & (PBUF - 1);
  int s = c >> 1, b = c & 1;
  size_t pj = (size_t)(b * PBUF + j);

  const float* dsrc = s == 0 ? xyz2 : xyz1;
  const float* dh = s == 0 ? hsv2 : hsv1;
  const float* dn = s == 0 ? normal2 : normal1;
  const float* dr = s == 0 ? nres2 : nres1;
  const float* R  = (s == 0 ? R12 : R21) + b * 9;
  const float* tt = (s == 0 ? t12 : t21) + b * 3;
  int ldb = (s == 0 ? npts2 : npts1)[b];
  if (j < ldb) {
    const float* x = dsrc + pj * 3;
    float y0 = xformRow(R + 0, tt[0], x[0], x[1], x[2]);
    float y1 = xformRow(R + 3, tt[1], x[0], x[1], x[2]);
    float y2 = xformRow(R + 6, tt[2], x[0], x[1], x[2]);
    const float* n = dn + pj * 3;
    float n0 = xformRow(R + 0, 0.f, n[0], n[1], n[2]);
    float n1 = xformRow(R + 3, 0.f, n[0], n[1], n[2]);
    float n2 = xformRow(R + 6, 0.f, n[0], n[1], n[2]);
    const float* h = dh + pj * 3;
    float r = dr[pj];
    int bin = binOfZ(y2) * NYB + binOfY(y1);
    int pos = atomicAdd((int*)(ws + OFF_DBCUR) + c * NBINS + bin, 1) + c * PBUF;
    ((float4*)(ws + OFF_DBPOS))[pos] = make_float4(y0, y1, y2, 0.f);
    ((float4*)(ws + OFF_DBF1))[pos] = make_float4(h[0], h[1], h[2], r);  // hsv, nres
    ((float4*)(ws + OFF_DBF2))[pos] = make_float4(n0, n1, n2, 0.f);      // normal
  }
}

// ---------------- K3: main. 1 wave/query; (z,y)-window walk + ballot compaction +
// branch-free LDS rank-select (replaces bitonic/extraction shuffle chains) + fused finalize.
__global__ __launch_bounds__(256) void k_main(
    const float* xyz1, const float* xyz2,
    const float* hsv1, const float* hsv2,
    const float* normal1, const float* normal2,
    const float* nres1, const float* nres2,
    const int* npts1, const int* npts2, char* ws, float* out) {
  __shared__ unsigned sBuf[4 * (CAP + 4)];   // +4 sentinel pad per wave; 1040 B stride (16-aligned)
  __shared__ bool sLast;
  const int lane = threadIdx.x & 63;
  const int wIn = threadIdx.x >> 6;
  const int gw = blockIdx.x * 4 + wIn;              // 0..32767
  const int c = gw >> 13;
  const int qi = (int)(__brev((unsigned)(gw & 8191)) >> 19);  // bit-reversed: load balance
  const int s = c >> 1, b = c & 1;
  const int lq = (s == 0 ? npts1 : npts2)[b];

  if (qi < lq) {                                    // wave-uniform guard (no early return: fused final below)
    // query data: raw (un-transformed) cloud, wave-uniform scalar loads
    const size_t qo = (size_t)(b * PBUF + qi);
    const float* qx = (s == 0 ? xyz1 : xyz2) + qo * 3;
    const float* qh = (s == 0 ? hsv1 : hsv2) + qo * 3;
    const float* qn = (s == 0 ? normal1 : normal2) + qo * 3;
    const float* qr = (s == 0 ? nres1 : nres2) + qo;
    const float qpx = qx[0], qpy = qx[1], qpz = qx[2];
    const float qh0 = qh[0], qh1 = qh[1], qh2 = qh[2];
    const float qn0 = qn[0], qn1 = qn[1], qn2 = qn[2];
    const float qres = qr[0];

    const float ell = fmaxf(0.015f * (qpz - 10.0f), 0.15f);
    const float ls = ell * ell;
    const float thrF = THR_MULT * ls;
    const float rad = sqrtf(thrF);
    const float inv_ls = 1.0f / ls;

    // window: z-bins [zlo,zhi] x y-bins [ylo,yhi]; flat lexicographic prefix F
    const int* F = (const int*)(ws + OFF_DBSTART) + c * (NBINS + 1);
    const int zlo = binOfZ(qpz - rad), zhi = binOfZ(qpz + rad);
    const int ylo = binOfY(qpy - rad), yhi = binOfY(qpy + rad);
    const int nseg = zhi - zlo + 1;                 // <= 14

    int segS = 0, segLen = 0;
    if (lane < nseg) {
      int zk = zlo + lane;
      segS = F[zk * NYB + ylo];
      segLen = F[zk * NYB + yhi + 1] - segS;        // yhi=31 rolls into next z-bin start: correct
    }
    int cum = segLen;
    #pragma unroll
    for (int o = 1; o < 64; o <<= 1) {
      int n = __shfl_up(cum, o);
      if (lane >= o) cum += n;
    }
    const int L = __shfl(cum, 63);
    const int excl = cum - segLen;

    const float4* dbPos = (const float4*)(ws + OFF_DBPOS) + c * PBUF;
    const float4* dbF1  = (const float4*)(ws + OFF_DBF1) + c * PBUF;
    const float4* dbF2  = (const float4*)(ws + OFF_DBF2) + c * PBUF;

    unsigned* buf = sBuf + wIn * (CAP + 4);
    int pos = 0;
    for (int base = 0; base < L; base += 64) {
      int t = base + lane;
      bool in = t < L;
      int tc = min(t, L - 1);
      int kk = 0;                                   // binary search: largest k with excl[k] <= tc
      #pragma unroll
      for (int step = 8; step; step >>= 1) {
        int cnd = kk + step;
        int e = __shfl(excl, cnd & 63);
        if (cnd < nseg && e <= tc) kk = cnd;
      }
      int j = __shfl(segS, kk) + (tc - __shfl(excl, kk));
      float4 p = dbPos[j];
      float dx = p.x - qpx, dy = p.y - qpy, dz = p.z - qpz;
      float d2 = __fmaf_rn(dx, dx, __fmaf_rn(dy, dy, dz * dz));
      bool keep = in && (d2 <= thrF);
      unsigned long long m = __ballot(keep);
      int rank = (int)__popcll(m & ((1ull << lane) - 1ull));
      if (keep) {
        int pidx = pos + rank;
        if (pidx < CAP) buf[pidx] = (__float_as_uint(d2) & D2_MASK) | (unsigned)j;
      }
      pos += (int)__popcll(m);
    }
    pos = min(pos, CAP);

    // ---- rank-select: each lane owns 4 slots; rank vs all survivors via broadcast
    // LDS chunk reads (pure VALU, no dependent shuffle chains). rank<KNN => in top-20.
    if (lane < 4) buf[pos + lane] = KEY_INF;        // sentinel pad to uint4 boundary
    unsigned r0 = (lane       < pos) ? buf[lane]       : KEY_INF;
    unsigned r1 = (lane + 64  < pos) ? buf[lane + 64]  : KEY_INF;
    unsigned r2 = (lane + 128 < pos) ? buf[lane + 128] : KEY_INF;
    unsigned r3 = (lane + 192 < pos) ? buf[lane + 192] : KEY_INF;
    int k0 = 0, k1 = 0, k2 = 0, k3 = 0;
    const int nch = (pos + 3) >> 2;
    const uint4* b4 = (const uint4*)buf;
    for (int ch = 0; ch < nch; ++ch) {
      uint4 q4 = b4[ch];                            // same addr across lanes: broadcast, conflict-free
      k0 += (q4.x < r0) + (q4.y < r0) + (q4.z < r0) + (q4.w < r0);
      k1 += (q4.x < r1) + (q4.y < r1) + (q4.z < r1) + (q4.w < r1);
      k2 += (q4.x < r2) + (q4.y < r2) + (q4.z < r2) + (q4.w < r2);
      k3 += (q4.x < r3) + (q4.y < r3) + (q4.z < r3) + (q4.w < r3);
    }

    // evaluate selected keys in place (owner lane accumulates; keys unique, exactly min(pos,20) pass)
    auto evalKey = [&](unsigned key, int rk) -> float {
      if (rk >= KNN || key == KEY_INF) return 0.f;
      int j = (int)(key & IDX_MASK);
      float4 p = dbPos[j];
      float4 f1 = dbF1[j];
      float4 f2 = dbF2[j];
      float dx = p.x - qpx, dy = p.y - qpy, dz = p.z - qpz;
      float d2 = __fmaf_rn(dx, dx, __fmaf_rn(dy, dy, dz * dz));   // exact d2
      float dist_k = __expf(-d2 * inv_ls);
      float c0 = qh0 - f1.x, c1 = qh1 - f1.y, c2 = qh2 - f1.z;
      float cd = sqrtf(__fmaf_rn(c0, c0, __fmaf_rn(c1, c1, c2 * c2)) + 1e-12f);
      float color_k = __expf(cd * -5.0f);
      float alpha = 0.2f / (0.1f + qres + f1.w);
      float nd = __fmaf_rn(qn0, f2.x, __fmaf_rn(qn1, f2.y, qn2 * f2.z));
      float nk = fmaxf(nd * alpha, 0.0f);
      return dist_k * color_k * nk;
    };
    float lsum = evalKey(r0, k0) + evalKey(r1, k1) + evalKey(r2, k2) + evalKey(r3, k3);

    #pragma unroll
    for (int o = 32; o; o >>= 1) lsum += __shfl_down(lsum, o);
    if (lane == 0)
      atomicAdd((float*)(ws + OFF_ACCUM) + (s * 256 + (blockIdx.x & 255)), lsum);
  }

  // ---- fused finalize: last block to finish reduces the 2x256 accum cells
  __syncthreads();
  if (threadIdx.x == 0) {
    __threadfence();
    sLast = atomicAdd((unsigned*)(ws + OFF_DONE), 1u) == (unsigned)(gridDim.x - 1);
  }
  __syncthreads();
  if (sLast && threadIdx.x < 64) {
    float* acc = (float*)(ws + OFF_ACCUM);
    float s1 = 0.f, s2 = 0.f;
    #pragma unroll
    for (int i = 0; i < 4; ++i) {                   // atomic-0 reads: device-scope coherent across XCDs
      s1 += atomicAdd(acc + (threadIdx.x + 64 * i), 0.0f);
      s2 += atomicAdd(acc + (256 + threadIdx.x + 64 * i), 0.0f);
    }
    #pragma unroll
    for (int o = 32; o; o >>= 1) {
      s1 += __shfl_down(s1, o);
      s2 += __shfl_down(s2, o);
    }
    if (threadIdx.x == 0) {
      float k1 = s1 / (20.0f * (float)(npts1[0] + npts1[1]));
      float k2 = s2 / (20.0f * (float)(npts2[0] + npts2[1]));
      out[0] = 0.5f * (k1 + k2);
    }
  }
}

extern "C" void kernel_launch(void* const* d_in, const int* in_sizes, int n_in,
                              void* d_out, int out_size, void* d_ws, size_t ws_size,
                              hipStream_t stream) {
  const float* xyz1 = (const float*)d_in[0];
  const float* xyz2 = (const float*)d_in[1];
  const float* hsv1 = (const float*)d_in[2];
  const float* hsv2 = (const float*)d_in[3];
  const float* normal1 = (const float*)d_in[4];
  const float* normal2 = (const float*)d_in[5];
  const float* nres1 = (const float*)d_in[6];
  const float* nres2 = (const float*)d_in[7];
  const float* R12 = (const float*)d_in[8];
  const float* t12 = (const float*)d_in[9];
  const float* R21 = (const float*)d_in[10];
  const float* t21 = (const float*)d_in[11];
  const int* npts1 = (const int*)d_in[12];
  const int* npts2 = (const int*)d_in[13];
  char* ws = (char*)d_ws;
  float* out = (float*)d_out;

  // 3 dispatches total (was 6: memset+count+prefix+scatter+main+final)
  k_cp<<<dim3(NCOMBO), dim3(256), 0, stream>>>(
      xyz1, xyz2, R12, t12, R21, t21, npts1, npts2, ws);
  k_scatter<<<dim3(NCOMBO * PBUF / 256), dim3(256), 0, stream>>>(
      xyz1, xyz2, hsv1, hsv2, normal1, normal2, nres1, nres2,
      R12, t12, R21, t21, npts1, npts2, ws);
  k_main<<<dim3(NCOMBO * PBUF / 4), dim3(256), 0, stream>>>(
      xyz1, xyz2, hsv1, hsv2, normal1, normal2, nres1, nres2, npts1, npts2, ws, out);
}

// Round 2
// 140.741 us; speedup vs baseline: 1.8470x; 1.8470x over previous
//
#include <hip/hip_runtime.h>
#include <cstdint>
#include <cstddef>

// Problem constants (from reference: B=2, P=8192, K=20)
#define PBUF 8192
#define NZB 256            // z bins
#define NYB 32             // y bins within each z bin (lexicographic sort key)
#define NBINS (NZB * NYB)  // 8192 flat bins per combo
#define NCOMBO 4           // (side, batch) combos: c = side*2 + b
#define KNN 20
#define CAP 256            // survivor cap per query (expected <=130)

// binning: transformed coords bounded by ~|v|<=64; [-72,72] covers all
#define ZMIN_F (-72.0f)
#define INV_BINW (256.0f / 144.0f)
#define INV_YBINW (32.0f / 144.0f)

#define IDX_MASK 0x1FFFu
#define D2_MASK 0xFFFFE000u
#define KEY_INF 0xFFFFFFFFu

// eps-filter: terms with d2 > 21*ls contribute < 2exp(-21) each; worst-case induced
// output error <= ~1e-9 << 1.69e-8 abs threshold (ref value ~8.5e-7).
#define THR_MULT 21.0f

// workspace layout (bytes)
#define OFF_ACCUM   0                                       // 512 floats: [side][256 cells]
#define OFF_DBSTART 2064                                    // 4 * 8193 ints (flat (z,y) prefix)
#define OFF_DBCUR   (OFF_DBSTART + NCOMBO * (NBINS + 1) * 4)   // 4 * 8192 ints (cursors)
#define OFF_DBPOS   (OFF_DBCUR + NCOMBO * NBINS * 4)        // 16-aligned
#define ARR_BYTES   (NCOMBO * PBUF * 16)                    // 524288 per float4 array
#define OFF_DBF1    (OFF_DBPOS + ARR_BYTES)
#define OFF_DBF2    (OFF_DBF1 + ARR_BYTES)
// total ws use ~1.84 MB

__device__ __forceinline__ int binOfZ(float z) {
  int b = (int)floorf((z - ZMIN_F) * INV_BINW);
  return min(max(b, 0), NZB - 1);
}
__device__ __forceinline__ int binOfY(float y) {
  int b = (int)floorf((y - ZMIN_F) * INV_YBINW);
  return min(max(b, 0), NYB - 1);
}

// Pinned fma order so count-kernel and scatter-kernel binning agree bit-exactly.
__device__ __forceinline__ float xformRow(const float* R, float tr, float x0, float x1, float x2) {
  return __fmaf_rn(R[2], x2, __fmaf_rn(R[1], x1, __fmaf_rn(R[0], x0, tr)));
}

// ---------------- K1: fused zero + count + prefix. One block per combo, LDS histogram.
// Replaces {memset, k_count, k_prefix} with 1 dispatch; no global count atomics.
__global__ __launch_bounds__(256) void k_cp(
    const float* xyz1, const float* xyz2,
    const float* R12, const float* t12,
    const float* R21, const float* t21,
    const int* npts1, const int* npts2, char* ws) {
  __shared__ int hist[NBINS];   // 32 KB
  __shared__ int sTot[256];
  const int c = blockIdx.x, t = threadIdx.x;
  const int s = c >> 1, b = c & 1;

  #pragma unroll
  for (int k = 0; k < 32; ++k) hist[t + 256 * k] = 0;
  if (c == 0) {                 // zero accum cells (512 floats)
    int* z = (int*)ws;
    for (int i = t; i < 512; i += 256) z[i] = 0;
  }
  __syncthreads();

  const float* dsrc = s == 0 ? xyz2 : xyz1;
  const float* R  = (s == 0 ? R12 : R21) + b * 9;
  const float* tt = (s == 0 ? t12 : t21) + b * 3;
  const int ldb = (s == 0 ? npts2 : npts1)[b];

  for (int j = t; j < PBUF; j += 256) {
    if (j < ldb) {
      const float* x = dsrc + (size_t)(b * PBUF + j) * 3;
      float x0 = x[0], x1 = x[1], x2 = x[2];
      float y1 = xformRow(R + 3, tt[1], x0, x1, x2);
      float y2 = xformRow(R + 6, tt[2], x0, x1, x2);
      int bin = binOfZ(y2) * NYB + binOfY(y1);
      atomicAdd(&hist[bin], 1);
    }
  }
  __syncthreads();

  // exclusive prefix over 8192 bins: 32 per thread + 256-wide shared scan
  int vals[32];
  int base = t * 32;
  int sum = 0;
  #pragma unroll
  for (int k = 0; k < 32; ++k) { vals[k] = hist[base + k]; sum += vals[k]; }
  sTot[t] = sum;
  __syncthreads();
  for (int o = 1; o < 256; o <<= 1) {
    int v = (t >= o) ? sTot[t - o] : 0;
    __syncthreads();
    sTot[t] += v;
    __syncthreads();
  }
  int run = sTot[t] - sum;
  int* st  = (int*)(ws + OFF_DBSTART) + c * (NBINS + 1);
  int* cnt = (int*)(ws + OFF_DBCUR) + c * NBINS;
  #pragma unroll
  for (int k = 0; k < 32; ++k) {
    st[base + k] = run;
    cnt[base + k] = run;     // cursor init
    run += vals[k];
  }
  if (t == 255) st[NBINS] = run;
}

// ---------------- K2: scatter transformed db points + features, (z,y)-lexicographic order ----------------
__global__ void k_scatter(const float* xyz1, const float* xyz2,
                          const float* hsv1, const float* hsv2,
                          const float* normal1, const float* normal2,
                          const float* nres1, const float* nres2,
                          const float* R12, const float* t12,
                          const float* R21, const float* t21,
                          const int* npts1, const int* npts2, char* ws) {
  int tid = blockIdx.x * 256 + threadIdx.x;
  int c = tid >> 13, j = tid & (PBUF - 1);
  int s = c >> 1, b = c & 1;
  size_t pj = (size_t)(b * PBUF + j);

  const float* dsrc = s == 0 ? xyz2 : xyz1;
  const float* dh = s == 0 ? hsv2 : hsv1;
  const float* dn = s == 0 ? normal2 : normal1;
  const float* dr = s == 0 ? nres2 : nres1;
  const float* R  = (s == 0 ? R12 : R21) + b * 9;
  const float* tt = (s == 0 ? t12 : t21) + b * 3;
  int ldb = (s == 0 ? npts2 : npts1)[b];
  if (j < ldb) {
    const float* x = dsrc + pj * 3;
    float y0 = xformRow(R + 0, tt[0], x[0], x[1], x[2]);
    float y1 = xformRow(R + 3, tt[1], x[0], x[1], x[2]);
    float y2 = xformRow(R + 6, tt[2], x[0], x[1], x[2]);
    const float* n = dn + pj * 3;
    float n0 = xformRow(R + 0, 0.f, n[0], n[1], n[2]);
    float n1 = xformRow(R + 3, 0.f, n[0], n[1], n[2]);
    float n2 = xformRow(R + 6, 0.f, n[0], n[1], n[2]);
    const float* h = dh + pj * 3;
    float r = dr[pj];
    int bin = binOfZ(y2) * NYB + binOfY(y1);
    int pos = atomicAdd((int*)(ws + OFF_DBCUR) + c * NBINS + bin, 1) + c * PBUF;
    ((float4*)(ws + OFF_DBPOS))[pos] = make_float4(y0, y1, y2, 0.f);
    ((float4*)(ws + OFF_DBF1))[pos] = make_float4(h[0], h[1], h[2], r);  // hsv, nres
    ((float4*)(ws + OFF_DBF2))[pos] = make_float4(n0, n1, n2, 0.f);      // normal
  }
}

// ---------------- K3: main. 1 wave/query; (z,y)-window walk + ballot compaction +
// branch-free LDS rank-select. NO block-level coupling: waves retire independently.
__global__ __launch_bounds__(256) void k_main(
    const float* xyz1, const float* xyz2,
    const float* hsv1, const float* hsv2,
    const float* normal1, const float* normal2,
    const float* nres1, const float* nres2,
    const int* npts1, const int* npts2, char* ws) {
  __shared__ unsigned sBuf[4 * (CAP + 4)];   // +4 sentinel pad per wave; 1040 B stride (16-aligned)
  const int lane = threadIdx.x & 63;
  const int wIn = threadIdx.x >> 6;
  const int gw = blockIdx.x * 4 + wIn;              // 0..32767
  const int c = gw >> 13;
  const int qi = (int)(__brev((unsigned)(gw & 8191)) >> 19);  // bit-reversed: load balance
  const int s = c >> 1, b = c & 1;
  const int lq = (s == 0 ? npts1 : npts2)[b];
  if (qi >= lq) return;                             // wave-uniform

  // query data: raw (un-transformed) cloud, wave-uniform scalar loads
  const size_t qo = (size_t)(b * PBUF + qi);
  const float* qx = (s == 0 ? xyz1 : xyz2) + qo * 3;
  const float* qh = (s == 0 ? hsv1 : hsv2) + qo * 3;
  const float* qn = (s == 0 ? normal1 : normal2) + qo * 3;
  const float* qr = (s == 0 ? nres1 : nres2) + qo;
  const float qpx = qx[0], qpy = qx[1], qpz = qx[2];
  const float qh0 = qh[0], qh1 = qh[1], qh2 = qh[2];
  const float qn0 = qn[0], qn1 = qn[1], qn2 = qn[2];
  const float qres = qr[0];

  const float ell = fmaxf(0.015f * (qpz - 10.0f), 0.15f);
  const float ls = ell * ell;
  const float thrF = THR_MULT * ls;
  const float rad = sqrtf(thrF);
  const float inv_ls = 1.0f / ls;

  // window: z-bins [zlo,zhi] x y-bins [ylo,yhi]; flat lexicographic prefix F
  const int* F = (const int*)(ws + OFF_DBSTART) + c * (NBINS + 1);
  const int zlo = binOfZ(qpz - rad), zhi = binOfZ(qpz + rad);
  const int ylo = binOfY(qpy - rad), yhi = binOfY(qpy + rad);
  const int nseg = zhi - zlo + 1;                   // <= 14

  int segS = 0, segLen = 0;
  if (lane < nseg) {
    int zk = zlo + lane;
    segS = F[zk * NYB + ylo];
    segLen = F[zk * NYB + yhi + 1] - segS;          // yhi=31 rolls into next z-bin start: correct
  }
  int cum = segLen;
  #pragma unroll
  for (int o = 1; o < 64; o <<= 1) {
    int n = __shfl_up(cum, o);
    if (lane >= o) cum += n;
  }
  const int L = __shfl(cum, 63);
  const int excl = cum - segLen;

  const float4* dbPos = (const float4*)(ws + OFF_DBPOS) + c * PBUF;
  const float4* dbF1  = (const float4*)(ws + OFF_DBF1) + c * PBUF;
  const float4* dbF2  = (const float4*)(ws + OFF_DBF2) + c * PBUF;

  unsigned* buf = sBuf + wIn * (CAP + 4);
  int pos = 0;
  for (int base = 0; base < L; base += 64) {
    int t = base + lane;
    bool in = t < L;
    int tc = min(t, L - 1);
    int kk = 0;                                     // binary search: largest k with excl[k] <= tc
    #pragma unroll
    for (int step = 8; step; step >>= 1) {
      int cnd = kk + step;
      int e = __shfl(excl, cnd & 63);
      if (cnd < nseg && e <= tc) kk = cnd;
    }
    int j = __shfl(segS, kk) + (tc - __shfl(excl, kk));
    float4 p = dbPos[j];
    float dx = p.x - qpx, dy = p.y - qpy, dz = p.z - qpz;
    float d2 = __fmaf_rn(dx, dx, __fmaf_rn(dy, dy, dz * dz));
    bool keep = in && (d2 <= thrF);
    unsigned long long m = __ballot(keep);
    int rank = (int)__popcll(m & ((1ull << lane) - 1ull));
    if (keep) {
      int pidx = pos + rank;
      if (pidx < CAP) buf[pidx] = (__float_as_uint(d2) & D2_MASK) | (unsigned)j;
    }
    pos += (int)__popcll(m);
  }
  pos = min(pos, CAP);

  // ---- rank-select: each lane owns 4 slots; rank vs all survivors via broadcast
  // LDS chunk reads (pure VALU, no dependent shuffle chains). rank<KNN => in top-20.
  if (lane < 4) buf[pos + lane] = KEY_INF;          // sentinel pad to uint4 boundary
  unsigned r0 = (lane       < pos) ? buf[lane]       : KEY_INF;
  unsigned r1 = (lane + 64  < pos) ? buf[lane + 64]  : KEY_INF;
  unsigned r2 = (lane + 128 < pos) ? buf[lane + 128] : KEY_INF;
  unsigned r3 = (lane + 192 < pos) ? buf[lane + 192] : KEY_INF;
  int k0 = 0, k1 = 0, k2 = 0, k3 = 0;
  const int nch = (pos + 3) >> 2;
  const uint4* b4 = (const uint4*)buf;
  for (int ch = 0; ch < nch; ++ch) {
    uint4 q4 = b4[ch];                              // same addr across lanes: broadcast, conflict-free
    k0 += (q4.x < r0) + (q4.y < r0) + (q4.z < r0) + (q4.w < r0);
    k1 += (q4.x < r1) + (q4.y < r1) + (q4.z < r1) + (q4.w < r1);
    k2 += (q4.x < r2) + (q4.y < r2) + (q4.z < r2) + (q4.w < r2);
    k3 += (q4.x < r3) + (q4.y < r3) + (q4.z < r3) + (q4.w < r3);
  }

  // evaluate selected keys in place (owner lane accumulates; keys unique, exactly min(pos,20) pass)
  auto evalKey = [&](unsigned key, int rk) -> float {
    if (rk >= KNN || key == KEY_INF) return 0.f;
    int j = (int)(key & IDX_MASK);
    float4 p = dbPos[j];
    float4 f1 = dbF1[j];
    float4 f2 = dbF2[j];
    float dx = p.x - qpx, dy = p.y - qpy, dz = p.z - qpz;
    float d2 = __fmaf_rn(dx, dx, __fmaf_rn(dy, dy, dz * dz));   // exact d2
    float dist_k = __expf(-d2 * inv_ls);
    float c0 = qh0 - f1.x, c1 = qh1 - f1.y, c2 = qh2 - f1.z;
    float cd = sqrtf(__fmaf_rn(c0, c0, __fmaf_rn(c1, c1, c2 * c2)) + 1e-12f);
    float color_k = __expf(cd * -5.0f);
    float alpha = 0.2f / (0.1f + qres + f1.w);
    float nd = __fmaf_rn(qn0, f2.x, __fmaf_rn(qn1, f2.y, qn2 * f2.z));
    float nk = fmaxf(nd * alpha, 0.0f);
    return dist_k * color_k * nk;
  };
  float lsum = evalKey(r0, k0) + evalKey(r1, k1) + evalKey(r2, k2) + evalKey(r3, k3);

  #pragma unroll
  for (int o = 32; o; o >>= 1) lsum += __shfl_down(lsum, o);
  if (lane == 0)
    atomicAdd((float*)(ws + OFF_ACCUM) + (s * 256 + (blockIdx.x & 255)), lsum);
}

// ---------------- K4: finalize (reduce 2x256 cells) ----------------
__global__ void k_final(const int* npts1, const int* npts2, const char* ws, float* out) {
  int lane = threadIdx.x;   // 64
  const float* acc = (const float*)(ws + OFF_ACCUM);
  float s1 = acc[lane] + acc[lane + 64] + acc[lane + 128] + acc[lane + 192];
  float s2 = acc[256 + lane] + acc[256 + lane + 64] + acc[256 + lane + 128] + acc[256 + lane + 192];
  #pragma unroll
  for (int o = 32; o; o >>= 1) {
    s1 += __shfl_down(s1, o);
    s2 += __shfl_down(s2, o);
  }
  if (lane == 0) {
    float k1 = s1 / (20.0f * (float)(npts1[0] + npts1[1]));
    float k2 = s2 / (20.0f * (float)(npts2[0] + npts2[1]));
    out[0] = 0.5f * (k1 + k2);
  }
}

extern "C" void kernel_launch(void* const* d_in, const int* in_sizes, int n_in,
                              void* d_out, int out_size, void* d_ws, size_t ws_size,
                              hipStream_t stream) {
  const float* xyz1 = (const float*)d_in[0];
  const float* xyz2 = (const float*)d_in[1];
  const float* hsv1 = (const float*)d_in[2];
  const float* hsv2 = (const float*)d_in[3];
  const float* normal1 = (const float*)d_in[4];
  const float* normal2 = (const float*)d_in[5];
  const float* nres1 = (const float*)d_in[6];
  const float* nres2 = (const float*)d_in[7];
  const float* R12 = (const float*)d_in[8];
  const float* t12 = (const float*)d_in[9];
  const float* R21 = (const float*)d_in[10];
  const float* t21 = (const float*)d_in[11];
  const int* npts1 = (const int*)d_in[12];
  const int* npts2 = (const int*)d_in[13];
  char* ws = (char*)d_ws;
  float* out = (float*)d_out;

  // 4 dispatches (was 6 in round 0; round 1's fused finalize regressed: serialized
  // same-address device atomics + threadfence per block = ~120us stall tail)
  k_cp<<<dim3(NCOMBO), dim3(256), 0, stream>>>(
      xyz1, xyz2, R12, t12, R21, t21, npts1, npts2, ws);
  k_scatter<<<dim3(NCOMBO * PBUF / 256), dim3(256), 0, stream>>>(
      xyz1, xyz2, hsv1, hsv2, normal1, normal2, nres1, nres2,
      R12, t12, R21, t21, npts1, npts2, ws);
  k_main<<<dim3(NCOMBO * PBUF / 4), dim3(256), 0, stream>>>(
      xyz1, xyz2, hsv1, hsv2, normal1, normal2, nres1, nres2, npts1, npts2, ws);
  k_final<<<dim3(1), dim3(64), 0, stream>>>(npts1, npts2, ws, out);
}